// Round 6
// baseline (40982.086 us; speedup 1.0000x reference)
//
#include <hip/hip_runtime.h>
#include <hip/hip_bf16.h>

// RelayTransformer forward, MI355X. Round 6: R5 pipeline + FP32 OUTPUT (d_out is
// float* per reference output dtype — the R4/R5 failure was writing bf16).
// B=2 T=2048 D=1024 H=8 dh=128, stitched S=2064, NT=4128.

constexpr int B_ = 2;
constexpr int T_ = 2048;
constexpr int D_ = 1024;
constexpr int SL_ = 2064;
constexpr int NT_ = 4128;
constexpr int DEPTH_ = 2;

__device__ inline float ldd(const void* p, size_t i, int f32) {
  return f32 ? ((const float*)p)[i]
             : __bfloat162float(((const __hip_bfloat16*)p)[i]);
}

// flags[0]=x-is-fp32, flags[1]=weights-are-fp32
__global__ void sniff_k(const unsigned* __restrict__ x, const unsigned* __restrict__ w,
                        int* __restrict__ flags) {
  __shared__ int cx, cw;
  int tid = threadIdx.x;
  if (tid == 0) { cx = 0; cw = 0; }
  __syncthreads();
  int ex = (x[tid] >> 7) & 0xFF;   // low-half bf16 exponent field
  if (ex >= 100 && ex <= 150) atomicAdd(&cx, 1);
  int ew = (w[tid] >> 7) & 0xFF;
  if (ew >= 100 && ew <= 150) atomicAdd(&cw, 1);
  __syncthreads();
  if (tid == 0) { flags[0] = (cx > 180) ? 0 : 1; flags[1] = (cw > 180) ? 0 : 1; }
}

__global__ __launch_bounds__(256) void wsfail_k(float* __restrict__ out, int n, float v) {
  int i = blockIdx.x * 256 + threadIdx.x;
  if (i < n) out[i] = v;
}

// ---------------- init: build xw (b, n, 129, d) ----------------
__global__ __launch_bounds__(256) void init_xw_k(const void* x, const void* relay,
                                                 const int* __restrict__ flags,
                                                 float* __restrict__ xw) {
  int idx = blockIdx.x * 256 + threadIdx.x;
  if (idx >= NT_ * D_) return;
  int d = idx & 1023;
  int r = idx >> 10;
  int b = r / SL_;
  int rem = r - b * SL_;
  int i = rem / 129;
  int p = rem - i * 129;
  float v;
  if (p == 0) v = ldd(relay, d, flags[1]);
  else v = ldd(x, ((size_t)(b * T_ + i * 128 + (p - 1))) * D_ + d, flags[0]);
  xw[idx] = v;
}

// ---------------- final: strip relay tokens, emit FP32 ----------------
__global__ __launch_bounds__(256) void final_k(const float* __restrict__ xw,
                                               float* __restrict__ out) {
  int idx = blockIdx.x * 256 + threadIdx.x;
  if (idx >= B_ * T_ * D_) return;
  int d = idx & 1023;
  int t = (idx >> 10) & 2047;
  int b = idx >> 21;
  int i = t >> 7, j = t & 127;
  out[idx] = xw[((size_t)(b * SL_ + i * 129 + 1 + j)) * D_ + d];
}

// ---------------- LayerNorm: strided fp32 in -> contiguous fp32 out (LDS tree) -----
__global__ __launch_bounds__(256) void ln_k(const float* __restrict__ in,
                                            float* __restrict__ out,
                                            const void* g, const void* be, size_t poff,
                                            const int* __restrict__ flags,
                                            int rows_per_chunk, long long chunk_stride,
                                            long long row_stride) {
  const int f32 = flags[1];
  const int r = blockIdx.x;
  const int tid = threadIdx.x;
  long long base = (long long)(r / rows_per_chunk) * chunk_stride
                 + (long long)(r % rows_per_chunk) * row_stride;
  const float* x = in + base;
  __shared__ float red[256];
  float v[4];
  float s = 0.f;
#pragma unroll
  for (int i = 0; i < 4; ++i) { v[i] = x[tid + 256 * i]; s += v[i]; }
  red[tid] = s;
  __syncthreads();
  for (int off = 128; off; off >>= 1) {
    if (tid < off) red[tid] += red[tid + off];
    __syncthreads();
  }
  float mean = red[0] * (1.f / 1024.f);
  __syncthreads();
  float q = 0.f;
#pragma unroll
  for (int i = 0; i < 4; ++i) { float dv = v[i] - mean; q += dv * dv; }
  red[tid] = q;
  __syncthreads();
  for (int off = 128; off; off >>= 1) {
    if (tid < off) red[tid] += red[tid + off];
    __syncthreads();
  }
  float inv = rsqrtf(red[0] * (1.f / 1024.f) + 1e-5f);
  float* o = out + (size_t)r * 1024;
#pragma unroll
  for (int i = 0; i < 4; ++i) {
    int d = tid + 256 * i;
    o[d] = (v[i] - mean) * inv * ldd(g, poff + d, f32) + ldd(be, poff + d, f32);
  }
}

// ---------------- naive GEMM: C[m,n] = act(A[m,:]@W[:,n] + bias) ----------------
__global__ __launch_bounds__(256) void ngemm_k(const float* __restrict__ A,
                                               const void* W, size_t woff,
                                               const void* bias, size_t boff,
                                               int has_bias, int act,
                                               const int* __restrict__ flags,
                                               float* __restrict__ C,
                                               int M, int N, int K) {
  const int f32 = flags[1];
  size_t idx = (size_t)blockIdx.x * 256 + threadIdx.x;
  if (idx >= (size_t)M * N) return;
  int m = (int)(idx / N);
  int n = (int)(idx - (size_t)m * N);
  const float* a = A + (size_t)m * K;
  float acc = 0.f;
  if (f32) {
    const float* w = (const float*)W + woff + n;
#pragma unroll 4
    for (int k = 0; k < K; ++k) acc = fmaf(a[k], w[(size_t)k * N], acc);
  } else {
    const __hip_bfloat16* w = (const __hip_bfloat16*)W + woff + n;
#pragma unroll 4
    for (int k = 0; k < K; ++k) acc = fmaf(a[k], __bfloat162float(w[(size_t)k * N]), acc);
  }
  if (has_bias) acc += ldd(bias, boff + n, f32);
  if (act == 1) acc = (acc >= 0.f) ? acc : 0.01f * acc;
  C[idx] = acc;
}

// ---------------- naive GEMM residual: C[map(m),n] += A@W + bias ----------------
__global__ __launch_bounds__(256) void ngemm_resid_k(const float* __restrict__ A,
                                                     const void* W, size_t woff,
                                                     const void* bias, size_t boff,
                                                     const int* __restrict__ flags,
                                                     float* __restrict__ C,
                                                     int M, int N, int K,
                                                     int rows_per_chunk, long long chunk_stride,
                                                     long long row_stride) {
  const int f32 = flags[1];
  size_t idx = (size_t)blockIdx.x * 256 + threadIdx.x;
  if (idx >= (size_t)M * N) return;
  int m = (int)(idx / N);
  int n = (int)(idx - (size_t)m * N);
  const float* a = A + (size_t)m * K;
  float acc = 0.f;
  if (f32) {
    const float* w = (const float*)W + woff + n;
#pragma unroll 4
    for (int k = 0; k < K; ++k) acc = fmaf(a[k], w[(size_t)k * N], acc);
  } else {
    const __hip_bfloat16* w = (const __hip_bfloat16*)W + woff + n;
#pragma unroll 4
    for (int k = 0; k < K; ++k) acc = fmaf(a[k], __bfloat162float(w[(size_t)k * N]), acc);
  }
  acc += ldd(bias, boff + n, f32);
  long long base = (long long)(m / rows_per_chunk) * chunk_stride
                 + (long long)(m % rows_per_chunk) * row_stride;
  C[base + n] += acc;
}

// ---------------- relay attention: 16 tokens per batch, 8 heads (fp32) ----------------
__global__ __launch_bounds__(256) void relay_attn_k(const float* __restrict__ qkvr,
                                                    float* __restrict__ o_r) {
  int hh = blockIdx.x, b = blockIdx.y;
  __shared__ float q[16][128], kk[16][128], vv[16][128];
  __shared__ float s[16][17];
  int tid = threadIdx.x;
  for (int i = tid; i < 16 * 128; i += 256) {
    int t = i >> 7, d = i & 127;
    size_t base = (size_t)(b * 16 + t) * 3072 + hh * 128 + d;
    q[t][d] = qkvr[base];
    kk[t][d] = qkvr[base + 1024];
    vv[t][d] = qkvr[base + 2048];
  }
  __syncthreads();
  int i = tid >> 4, j = tid & 15;
  float acc = 0.f;
  for (int d = 0; d < 128; ++d) acc += q[i][d] * kk[j][d];
  s[i][j] = acc;
  __syncthreads();
  float m = -1e30f;
  for (int jj = 0; jj < 16; ++jj) m = fmaxf(m, s[i][jj]);
  float sum = 0.f;
  for (int jj = 0; jj < 16; ++jj) sum += expf(s[i][jj] - m);
  float p = expf(s[i][j] - m) / sum;
  __syncthreads();
  s[i][j] = p;
  __syncthreads();
  for (int idx = tid; idx < 16 * 128; idx += 256) {
    int t = idx >> 7, d = idx & 127;
    float a2 = 0.f;
    for (int jj = 0; jj < 16; ++jj) a2 += s[t][jj] * vv[jj][d];
    o_r[(size_t)(b * 16 + t) * 1024 + hh * 128 + d] = a2;
  }
}

// ---------------- per-batch full attention, 4 query rows per block (fp32) ----------------
__global__ __launch_bounds__(256) void attn_b_k(const float* __restrict__ qkvb,
                                                float* __restrict__ o) {
  const int S = SL_;
  const int q0 = blockIdx.x * 4;
  const int hh = blockIdx.y;
  __shared__ float qs[4][128];
  __shared__ float sc[4][SL_];
  __shared__ float red[256];
  __shared__ float ov[4][2][128];
  __shared__ float mxs[4], Ls[4];
  const int tid = threadIdx.x;
  for (int i = tid; i < 512; i += 256)
    qs[i >> 7][i & 127] = qkvb[(size_t)(q0 + (i >> 7)) * 3072 + hh * 128 + (i & 127)];
  __syncthreads();
  // scores
  for (int j = tid; j < S; j += 256) {
    const float4* K4 = (const float4*)(qkvb + (size_t)j * 3072 + 1024 + hh * 128);
    float a[4] = {};
    for (int d4 = 0; d4 < 32; ++d4) {
      float4 kv = K4[d4];
#pragma unroll
      for (int r = 0; r < 4; ++r)
        a[r] += qs[r][d4 * 4 + 0] * kv.x + qs[r][d4 * 4 + 1] * kv.y +
                qs[r][d4 * 4 + 2] * kv.z + qs[r][d4 * 4 + 3] * kv.w;
    }
#pragma unroll
    for (int r = 0; r < 4; ++r) sc[r][j] = a[r];
  }
  __syncthreads();
  // row max (LDS tree per r)
  for (int r = 0; r < 4; ++r) {
    float lm = -1e30f;
    for (int j = tid; j < S; j += 256) lm = fmaxf(lm, sc[r][j]);
    red[tid] = lm;
    __syncthreads();
    for (int off = 128; off; off >>= 1) {
      if (tid < off) red[tid] = fmaxf(red[tid], red[tid + off]);
      __syncthreads();
    }
    if (tid == 0) mxs[r] = red[0];
    __syncthreads();
  }
  // exp + sum
  for (int r = 0; r < 4; ++r) {
    float ls = 0.f;
    for (int j = tid; j < S; j += 256) {
      float e = expf(sc[r][j] - mxs[r]);
      sc[r][j] = e;
      ls += e;
    }
    red[tid] = ls;
    __syncthreads();
    for (int off = 128; off; off >>= 1) {
      if (tid < off) red[tid] += red[tid + off];
      __syncthreads();
    }
    if (tid == 0) Ls[r] = red[0];
    __syncthreads();
  }
  // P @ V
  const int d = tid & 127, half = tid >> 7;
  float acc[4] = {};
  for (int j = half; j < S; j += 2) {
    float v = qkvb[(size_t)j * 3072 + 2048 + hh * 128 + d];
#pragma unroll
    for (int r = 0; r < 4; ++r) acc[r] += sc[r][j] * v;
  }
#pragma unroll
  for (int r = 0; r < 4; ++r) ov[r][half][d] = acc[r];
  __syncthreads();
  if (tid < 128) {
#pragma unroll
    for (int r = 0; r < 4; ++r)
      o[(size_t)(q0 + r) * 1024 + hh * 128 + tid] = (ov[r][0][tid] + ov[r][1][tid]) / Ls[r];
  }
}

extern "C" void kernel_launch(void* const* d_in, const int* in_sizes, int n_in,
                              void* d_out, int out_size, void* d_ws, size_t ws_size,
                              hipStream_t stream) {
  const void* x      = d_in[0];
  const void* relay  = d_in[1];
  const void* r_ln_g = d_in[2];
  const void* r_ln_b = d_in[3];
  const void* r_qkv  = d_in[4];
  const void* r_ow   = d_in[5];
  const void* r_ob   = d_in[6];
  const void* l_ln_g = d_in[7];
  const void* l_ln_b = d_in[8];
  const void* l_qkv  = d_in[9];
  const void* l_ow   = d_in[10];
  const void* l_ob   = d_in[11];
  const void* f_ln_g = d_in[12];
  const void* f_ln_b = d_in[13];
  const void* f_w1   = d_in[14];
  const void* f_b1   = d_in[15];
  const void* f_w2   = d_in[16];
  const void* f_b2   = d_in[17];
  float* out = (float*)d_out;   // reference output dtype is float32
  const int out_n = B_ * T_ * D_;

  // ---- workspace layout (all fp32): xw | h | S1 | relay(hr,qkvr,orr) | flags ----
  const size_t xw_b  = (size_t)NT_ * D_ * 4;                  // 16.9 MB
  const size_t h_b   = (size_t)NT_ * D_ * 4;                  // 16.9 MB
  const size_t s1_b  = (size_t)SL_ * 3 * D_ * 4;              // 25.4 MB (per-batch qkv / ffn chunk)
  const size_t rel_b = (size_t)32 * (1024 + 3072 + 1024) * 4; // 0.66 MB
  const size_t REQ   = xw_b + h_b + s1_b + rel_b + 64;

  if (ws_size < REQ) {
    float v = 20000.f + 8.f * (float)(ws_size >> 20);
    wsfail_k<<<(out_n + 255) / 256, 256, 0, stream>>>(out, out_n, v);
    return;
  }

  char* wsb = (char*)d_ws;
  float* xw   = (float*)wsb;
  float* h    = (float*)(wsb + xw_b);
  float* S1   = (float*)(wsb + xw_b + h_b);
  float* hr   = (float*)(wsb + xw_b + h_b + s1_b);
  float* qkvr = hr + 32 * 1024;
  float* orr  = qkvr + 32 * 3072;
  int* flags  = (int*)(wsb + xw_b + h_b + s1_b + rel_b);

  const long long REL_CS = (long long)SL_ * 1024;   // batch stride (rows of xw)
  const long long REL_RS = (long long)129 * 1024;   // group stride

  sniff_k<<<1, 256, 0, stream>>>((const unsigned*)x, (const unsigned*)r_qkv, flags);
  init_xw_k<<<(NT_ * D_ + 255) / 256, 256, 0, stream>>>(x, relay, flags, xw);

  for (int l = 0; l < DEPTH_; ++l) {
    // ---- relay attention over the 32 relay rows ----
    ln_k<<<32, 256, 0, stream>>>(xw, hr, r_ln_g, r_ln_b, (size_t)l * 1024, flags,
                                 16, REL_CS, REL_RS);
    ngemm_k<<<(32 * 3072 + 255) / 256, 256, 0, stream>>>(
        hr, r_qkv, (size_t)l * 1024 * 3072, nullptr, 0, 0, 0, flags, qkvr, 32, 3072, 1024);
    relay_attn_k<<<dim3(8, 2), 256, 0, stream>>>(qkvr, orr);
    ngemm_resid_k<<<(32 * 1024 + 255) / 256, 256, 0, stream>>>(
        orr, r_ow, (size_t)l * 1024 * 1024, r_ob, (size_t)l * 1024, flags, xw,
        32, 1024, 1024, 16, REL_CS, REL_RS);
    // ---- full attention over stitched sequence (per batch) ----
    ln_k<<<NT_, 256, 0, stream>>>(xw, h, l_ln_g, l_ln_b, (size_t)l * 1024, flags,
                                  NT_, 0, 1024);
    for (int b = 0; b < B_; ++b) {
      float* hb = h + (size_t)b * SL_ * 1024;
      ngemm_k<<<((size_t)SL_ * 3072 + 255) / 256, 256, 0, stream>>>(
          hb, l_qkv, (size_t)l * 1024 * 3072, nullptr, 0, 0, 0, flags, S1, SL_, 3072, 1024);
      attn_b_k<<<dim3(SL_ / 4, 8), 256, 0, stream>>>(S1, hb);  // overwrite h rows with attn out
    }
    ngemm_resid_k<<<((size_t)NT_ * 1024 + 255) / 256, 256, 0, stream>>>(
        h, l_ow, (size_t)l * 1024 * 1024, l_ob, (size_t)l * 1024, flags, xw,
        NT_, 1024, 1024, NT_, 0, 1024);
    // ---- FFN (4 row-chunks of 1032) ----
    ln_k<<<NT_, 256, 0, stream>>>(xw, h, f_ln_g, f_ln_b, (size_t)l * 1024, flags,
                                  NT_, 0, 1024);
    for (int c = 0; c < 4; ++c) {
      const int CM = NT_ / 4;  // 1032
      float* hc  = h + (size_t)c * CM * 1024;
      float* xwc = xw + (size_t)c * CM * 1024;
      ngemm_k<<<((size_t)CM * 4096 + 255) / 256, 256, 0, stream>>>(
          hc, f_w1, (size_t)l * 1024 * 4096, f_b1, (size_t)l * 4096, 1, 1, flags, S1,
          CM, 4096, 1024);
      ngemm_resid_k<<<((size_t)CM * 1024 + 255) / 256, 256, 0, stream>>>(
          S1, f_w2, (size_t)l * 4096 * 1024, f_b2, (size_t)l * 1024, flags, xwc,
          CM, 1024, 4096, CM, 0, 1024);
    }
  }

  final_k<<<(out_n + 255) / 256, 256, 0, stream>>>(xw, out);
}